// Round 4
// baseline (187.891 us; speedup 1.0000x reference)
//
#include <hip/hip_runtime.h>

// Conv2d 3x3 pad1 stride1, x[1,256,224,224] f32, w[256,256,3,3] f32 -> out[256,224,224] f32
// Implicit GEMM: M=256 (co), N=50176 (h*224+w), K=2304 (tap-major: k = (dh*3+dw)*256 + ci)
// R10: R9's counted-vmcnt schedule on R7's geometry. 128x128 tile, 4 waves, wave-tile
//      64x64, grid (392,2)=784 (3.06 blocks/CU - no grid quantization hole). TRIPLE-
//      buffered BK=32 LDS (48KB -> still 3 blocks/CU), raw s_barrier + vmcnt(4) (never
//      0 in main loop) + lgkmcnt(0)+sched_barrier(0) + setprio around the 16-MFMA
//      cluster. R9 proved this schedule +23% per-CU; R9's loss was grid=196 only.

#define H 224
#define W 224
#define NPOS (H*W)          // 50176
#define CI 256
#define CO 256
#define KDIM 2304
#define HP 226              // padded
#define XP_ELEMS (HP*HP*CI) // 13,075,456 shorts
#define AP_ELEMS (CO*KDIM)  // 589,824 shorts

typedef __bf16 bf16x8 __attribute__((ext_vector_type(8)));
typedef float f32x4 __attribute__((ext_vector_type(4)));
typedef unsigned short u16x4 __attribute__((ext_vector_type(4)));
typedef unsigned short u16x8 __attribute__((ext_vector_type(8)));

__device__ __forceinline__ unsigned short f2bf(float f) {
    unsigned int u = __float_as_uint(f);
    u += 0x7fff + ((u >> 16) & 1);   // round-to-nearest-even
    return (unsigned short)(u >> 16);
}

__device__ __forceinline__ void load_lds16(const unsigned short* g, unsigned short* l) {
    __builtin_amdgcn_global_load_lds(
        (const __attribute__((address_space(1))) void*)g,
        (__attribute__((address_space(3))) void*)l,
        16, 0, 0);
}

// ---- fused prep (unchanged from R8): xtrans + weight transform + border zero ----
#define XT_BLOCKS 3136      // 784 * 4
#define WT_BLOCKS 256
#define BORDER_V8 28800     // 230,400 shorts / 8
#define ROW_V8 7232         // 226*256/8
__global__ void prep_kernel(const float* __restrict__ x, const float* __restrict__ w,
                            unsigned short* __restrict__ ap, unsigned short* __restrict__ xp) {
    __shared__ unsigned short smem[64 * 68];
    const int bx = blockIdx.x;
    const int t = threadIdx.x;

    if (bx < XT_BLOCKS) {
        const unsigned int pBase = (unsigned int)(bx % 784) * 64;
        const unsigned int ciBase = (unsigned int)(bx / 784) * 64;
        {
            const int p4 = (t & 15) * 4;
            const int c0 = t >> 4;               // 0..15
#pragma unroll
            for (int i = 0; i < 4; ++i) {
                const int ci_l = c0 + i * 16;
                const f32x4 v = *(const f32x4*)&x[(ciBase + ci_l) * NPOS + pBase + p4];
                u16x4 s;
                s[0] = f2bf(v[0]); s[1] = f2bf(v[1]); s[2] = f2bf(v[2]); s[3] = f2bf(v[3]);
                *(u16x4*)&smem[ci_l * 68 + p4] = s;
            }
        }
        __syncthreads();
        {
            const int ci0 = (t & 7) * 8;
            const int pr = t >> 3;               // 0..31
#pragma unroll
            for (int j = 0; j < 2; ++j) {
                const int p_l = pr + j * 32;
                const unsigned int p = pBase + p_l;
                const unsigned int hi = p / W, wi = p - hi * W;
                u16x8 v;
#pragma unroll
                for (int k = 0; k < 8; ++k) v[k] = smem[(ci0 + k) * 68 + p_l];
                *(u16x8*)&xp[((hi + 1) * HP + (wi + 1)) * CI + ciBase + ci0] = v;
            }
        }
    } else if (bx < XT_BLOCKS + WT_BLOCKS) {
        const int co = bx - XT_BLOCKS;
        const float* wc = w + co * KDIM;
#pragma unroll
        for (int i = 0; i < 9; ++i)
            smem[i * 256 + t] = f2bf(wc[i * 256 + t]);
        __syncthreads();
        unsigned short* apc = ap + co * KDIM;
#pragma unroll
        for (int tap = 0; tap < 9; ++tap)
            apc[tap * 256 + t] = smem[t * 9 + tap];
    } else {
        const int idx = (bx - XT_BLOCKS - WT_BLOCKS) * 256 + t;
        if (idx < BORDER_V8) {
            unsigned short* p;
            if (idx < 2 * ROW_V8) {
                const int r = idx / ROW_V8;
                const int off = idx - r * ROW_V8;
                p = xp + r * (225 * HP * CI) + off * 8;
            } else {
                const int i2 = idx - 2 * ROW_V8;
                const int seg = i2 >> 5;
                const int o = i2 & 31;
                const int hp = 1 + (seg >> 1);
                const int wp = (seg & 1) * 225;
                p = xp + (hp * HP + wp) * CI + o * 8;
            }
            *(u16x8*)p = (u16x8){0, 0, 0, 0, 0, 0, 0, 0};
        }
    }
}

// ---- implicit GEMM: 128x128 tile, 4 waves (2Mx2N), wave-tile 64x64, BK=32,
//      TRIPLE buffer + counted vmcnt. Per iter: 8 ds_read_b128 + 4 gload_lds ->
//      16 MFMA, 2 raw barriers, vmcnt(4).
// Pipeline proof: at iter kt after stage(kt+2): outstanding = kt+1's 4 + kt+2's 4.
//   vmcnt(4)+barrier => kt+1 landed before any thread's next-iter ds_reads.
//   Buffer (kt+2)%3 was read at iter kt-1; kt-1's trailing barrier seals its readers.
__global__ __launch_bounds__(256, 3) void gemm_conv_kernel(
    const unsigned short* __restrict__ Ap,   // [256][2304] bf16
    const unsigned short* __restrict__ Xp,   // [226][226][256] bf16
    float* __restrict__ out)                 // [256][50176]
{
    __shared__ unsigned short Als[3][4096];  // [buf][128 rows x 32] = 8KB each
    __shared__ unsigned short Bls[3][4096];

    const int tid = threadIdx.x;
    const int Nb = blockIdx.x;               // 0..391
    const int Mb = blockIdx.y;               // 0..1
    const int wave = tid >> 6;               // 0..3
    const int wm = wave >> 1;                // 0..1 (M half)
    const int wn = wave & 1;                 // 0..1 (N half)
    const int lane = tid & 63;
    const int ln15 = lane & 15;
    const int quad = lane >> 4;
    const int xsw = (quad ^ (ln15 & 3)) * 8; // chunk-XOR swizzle on read

    // ---- staging sources: 2 A-chunks + 2 B-chunks per thread per K-tile ----
    const int rl = lane >> 2;                // 0..15
    const int sc = (lane & 3) ^ (rl & 3);    // swizzled source chunk

    const unsigned short* a_src[2];
    const unsigned short* b_src[2];
#pragma unroll
    for (int j = 0; j < 2; ++j) {
        const int row = (wave * 2 + j) * 16 + rl;          // 0..127
        a_src[j] = Ap + (Mb * 128 + row) * KDIM + sc * 8;  // + kt*32
        unsigned int p = Nb * 128 + row;
        unsigned int hi = p / W, wi = p - hi * W;
        b_src[j] = Xp + (hi * HP + wi) * CI + sc * 8;      // + tap/ci offset
    }

    f32x4 acc[4][4];
#pragma unroll
    for (int mi = 0; mi < 4; ++mi)
#pragma unroll
        for (int ni = 0; ni < 4; ++ni)
            acc[mi][ni] = (f32x4){0.f, 0.f, 0.f, 0.f};

    auto stage = [&](int kt, int buf) {
        const int tap = kt >> 3;             // 0..8
        const int dh = tap / 3, dw = tap - dh * 3;
        const int boff = (dh * HP + dw) * CI + (kt & 7) * 32;
        const int aoff = kt * 32;
#pragma unroll
        for (int j = 0; j < 2; ++j) {
            load_lds16(a_src[j] + aoff, &Als[buf][(wave * 2 + j) * 512]);
            load_lds16(b_src[j] + boff, &Bls[buf][(wave * 2 + j) * 512]);
        }
    };

    bf16x8 af[4], bfr[4];
    const int aBase = (wm * 64 + ln15) * 32 + xsw;
    const int bBase = (wn * 64 + ln15) * 32 + xsw;

    auto ldAB = [&](int c) {
#pragma unroll
        for (int mi = 0; mi < 4; ++mi)
            af[mi] = *(const bf16x8*)&Als[c][aBase + mi * 16 * 32];
#pragma unroll
        for (int ni = 0; ni < 4; ++ni)
            bfr[ni] = *(const bf16x8*)&Bls[c][bBase + ni * 16 * 32];
    };
    auto mfma16 = [&]() {
        __builtin_amdgcn_s_setprio(1);
#pragma unroll
        for (int mi = 0; mi < 4; ++mi)
#pragma unroll
            for (int ni = 0; ni < 4; ++ni)
                acc[mi][ni] = __builtin_amdgcn_mfma_f32_16x16x32_bf16(
                    af[mi], bfr[ni], acc[mi][ni], 0, 0, 0);
        __builtin_amdgcn_s_setprio(0);
    };

    // ---- prologue: fill buffers 0,1; wait tile 0 only (8 outstanding, keep 4) ----
    stage(0, 0);
    stage(1, 1);
    asm volatile("s_waitcnt vmcnt(4)" ::: "memory");
    __builtin_amdgcn_s_barrier();

    int c = 0;                                             // kt % 3
    for (int kt = 0; kt < 70; ++kt) {
        const int s = (c == 0) ? 2 : c - 1;                // (kt+2) % 3
        ldAB(c);                                           // 8 ds_read_b128 (buf c)
        stage(kt + 2, s);                                  // 4 gload_lds -> buf s
        asm volatile("s_waitcnt vmcnt(4)" ::: "memory");   // kt+1 fully landed
        __builtin_amdgcn_s_barrier();
        asm volatile("s_waitcnt lgkmcnt(0)" ::: "memory");
        __builtin_amdgcn_sched_barrier(0);
        mfma16();
        __builtin_amdgcn_s_barrier();
        c = (c == 2) ? 0 : c + 1;
    }
    // ---- kt = 70: no staging; drain so tile 71 is landed ----
    {
        ldAB(c);
        asm volatile("s_waitcnt vmcnt(0)" ::: "memory");
        __builtin_amdgcn_s_barrier();
        asm volatile("s_waitcnt lgkmcnt(0)" ::: "memory");
        __builtin_amdgcn_sched_barrier(0);
        mfma16();
        __builtin_amdgcn_s_barrier();
        c = (c == 2) ? 0 : c + 1;
    }
    // ---- kt = 71: all resident, no LDS writers remain ----
    {
        ldAB(c);
        asm volatile("s_waitcnt lgkmcnt(0)" ::: "memory");
        __builtin_amdgcn_sched_barrier(0);
        mfma16();
    }

    // ---- epilogue: C/D layout col = lane&15 (n=p), row = quad*4 + reg (m=co) ----
    const int pcol = Nb * 128 + wn * 64 + ln15;
    const int corow = Mb * 128 + wm * 64 + quad * 4;
#pragma unroll
    for (int mi = 0; mi < 4; ++mi)
#pragma unroll
        for (int ni = 0; ni < 4; ++ni)
#pragma unroll
            for (int r = 0; r < 4; ++r)
                out[(corow + mi * 16 + r) * NPOS + pcol + ni * 16] = acc[mi][ni][r];
}

extern "C" void kernel_launch(void* const* d_in, const int* in_sizes, int n_in,
                              void* d_out, int out_size, void* d_ws, size_t ws_size,
                              hipStream_t stream) {
    const float* x = (const float*)d_in[0];       // [1,256,224,224]
    const float* w = (const float*)d_in[1];       // [256,256,3,3]
    float* out = (float*)d_out;                   // [256,224,224]

    unsigned short* xp = (unsigned short*)d_ws;        // 13,075,456 shorts
    unsigned short* ap = xp + XP_ELEMS;                // 589,824 shorts

    prep_kernel<<<XT_BLOCKS + WT_BLOCKS + 113, 256, 0, stream>>>(x, w, ap, xp);
    gemm_conv_kernel<<<dim3(NPOS / 128, CO / 128), 256, 0, stream>>>(ap, xp, out);
}

// Round 5
// 164.291 us; speedup vs baseline: 1.1436x; 1.1436x over previous
//
#include <hip/hip_runtime.h>

// Conv2d 3x3 pad1 stride1, x[1,256,224,224] f32, w[256,256,3,3] f32 -> out[256,224,224] f32
// Implicit GEMM: M=256 (co), N=50176 (h*224+w), K=2304 (tap-major: k = (dh*3+dw)*256 + ci)
// R11: faithful m201 8-phase port. BM=256 x BN=256, BK=64, 8 waves (2M x 4N), wave-tile
//      128x64 (intensity 42.7 FLOP/LDS-byte vs 32 at 64x64 - R6..R10 were LDS-read-bound,
//      MfmaUtil pinned at 22-26 regardless of schedule). 2 K-tile LDS buffers (128KB),
//      4 fine phases per K-tile: {ds_read 8|4 ; stage 1 half-tile ; [vmcnt(4) P2/P4] ;
//      bar ; lgkm0+sched_barrier ; setprio1 ; 16 MFMA ; setprio0 ; bar}. vmcnt never 0
//      in main loop. Conflict-free slot^(row&3) swizzle on 64B row-halves, inverse
//      pre-applied to global source (both-sides rule). Grid 196 (accepted 76.6% util).

#define H 224
#define W 224
#define NPOS (H*W)          // 50176
#define CI 256
#define CO 256
#define KDIM 2304
#define HP 226              // padded
#define XP_ELEMS (HP*HP*CI) // 13,075,456 shorts
#define AP_ELEMS (CO*KDIM)  // 589,824 shorts

typedef __bf16 bf16x8 __attribute__((ext_vector_type(8)));
typedef float f32x4 __attribute__((ext_vector_type(4)));
typedef unsigned short u16x4 __attribute__((ext_vector_type(4)));
typedef unsigned short u16x8 __attribute__((ext_vector_type(8)));

__device__ __forceinline__ unsigned short f2bf(float f) {
    unsigned int u = __float_as_uint(f);
    u += 0x7fff + ((u >> 16) & 1);   // round-to-nearest-even
    return (unsigned short)(u >> 16);
}

__device__ __forceinline__ void load_lds16(const unsigned short* g, unsigned short* l) {
    __builtin_amdgcn_global_load_lds(
        (const __attribute__((address_space(1))) void*)g,
        (__attribute__((address_space(3))) void*)l,
        16, 0, 0);
}

// ---- fused prep (unchanged from R8): xtrans + weight transform + border zero ----
#define XT_BLOCKS 3136      // 784 * 4
#define WT_BLOCKS 256
#define BORDER_V8 28800     // 230,400 shorts / 8
#define ROW_V8 7232         // 226*256/8
__global__ void prep_kernel(const float* __restrict__ x, const float* __restrict__ w,
                            unsigned short* __restrict__ ap, unsigned short* __restrict__ xp) {
    __shared__ unsigned short smem[64 * 68];
    const int bx = blockIdx.x;
    const int t = threadIdx.x;

    if (bx < XT_BLOCKS) {
        const unsigned int pBase = (unsigned int)(bx % 784) * 64;
        const unsigned int ciBase = (unsigned int)(bx / 784) * 64;
        {
            const int p4 = (t & 15) * 4;
            const int c0 = t >> 4;               // 0..15
#pragma unroll
            for (int i = 0; i < 4; ++i) {
                const int ci_l = c0 + i * 16;
                const f32x4 v = *(const f32x4*)&x[(ciBase + ci_l) * NPOS + pBase + p4];
                u16x4 s;
                s[0] = f2bf(v[0]); s[1] = f2bf(v[1]); s[2] = f2bf(v[2]); s[3] = f2bf(v[3]);
                *(u16x4*)&smem[ci_l * 68 + p4] = s;
            }
        }
        __syncthreads();
        {
            const int ci0 = (t & 7) * 8;
            const int pr = t >> 3;               // 0..31
#pragma unroll
            for (int j = 0; j < 2; ++j) {
                const int p_l = pr + j * 32;
                const unsigned int p = pBase + p_l;
                const unsigned int hi = p / W, wi = p - hi * W;
                u16x8 v;
#pragma unroll
                for (int k = 0; k < 8; ++k) v[k] = smem[(ci0 + k) * 68 + p_l];
                *(u16x8*)&xp[((hi + 1) * HP + (wi + 1)) * CI + ciBase + ci0] = v;
            }
        }
    } else if (bx < XT_BLOCKS + WT_BLOCKS) {
        const int co = bx - XT_BLOCKS;
        const float* wc = w + co * KDIM;
#pragma unroll
        for (int i = 0; i < 9; ++i)
            smem[i * 256 + t] = f2bf(wc[i * 256 + t]);
        __syncthreads();
        unsigned short* apc = ap + co * KDIM;
#pragma unroll
        for (int tap = 0; tap < 9; ++tap)
            apc[tap * 256 + t] = smem[t * 9 + tap];
    } else {
        const int idx = (bx - XT_BLOCKS - WT_BLOCKS) * 256 + t;
        if (idx < BORDER_V8) {
            unsigned short* p;
            if (idx < 2 * ROW_V8) {
                const int r = idx / ROW_V8;
                const int off = idx - r * ROW_V8;
                p = xp + r * (225 * HP * CI) + off * 8;
            } else {
                const int i2 = idx - 2 * ROW_V8;
                const int seg = i2 >> 5;
                const int o = i2 & 31;
                const int hp = 1 + (seg >> 1);
                const int wp = (seg & 1) * 225;
                p = xp + (hp * HP + wp) * CI + o * 8;
            }
            *(u16x8*)p = (u16x8){0, 0, 0, 0, 0, 0, 0, 0};
        }
    }
}

// ---- implicit GEMM, m201-style 8-phase, 256x256 tile, BK=64 ----
// LDS (shorts): A[pi][kappa] = 4 regions x 8192 at [0,32768); B likewise at +32768.
//   Region layout: 256 rows x 32 shorts (64B); slot s of row r holds global chunk
//   s^(r&3) (16B chunks). gload_lds writes linearly; inverse swizzle pre-applied to
//   the global source chunk per thread (c4 = (t&3)^((t>>2)&3)).
// Per K-tile kt (4 phases), staging kt+1 (buffer 1-pi, disjoint from reads):
//   P1: readA(k0,mi0-3)+readB(k0) [8 ds]; stage A-k0(kt+1); bar; lgkm0; 16 MFMA; bar
//   P2: readA(k0,mi4-7) [4 ds];    stage B-k0(kt+1); vmcnt(4); bar; lgkm0; 16 MFMA; bar
//   P3: readA(k1,mi0-3)+readB(k1); stage A-k1(kt+1); bar; lgkm0; 16 MFMA; bar
//   P4: readA(k1,mi4-7);           stage B-k1(kt+1); vmcnt(4); bar; lgkm0; 16 MFMA; bar
// vmcnt proof (loads/thread, issue order Ak0,Bk0,Ak1,Bk1 = 2 each):
//   at P4-end: outstanding = kt+1's 8 -> vmcnt(4) retires Ak0,Bk0(kt+1), read next P1. OK
//   at P2-end: outstanding = Ak1,Bk1(kt) 4 + Ak0,Bk0(kt+1) 4 -> vmcnt(4) retires
//   Ak1,Bk1(kt), read in P3. OK. Steady in-flight 4-8 loads, never drained to 0.
// Accumulation order per acc element: k ascending (k0 then k1 per kt) == R7 exactly.

#define READ_A(base, half)                                                      \
    _Pragma("unroll")                                                           \
    for (int mi = 0; mi < 4; ++mi)                                              \
        af[mi] = *(const bf16x8*)&lds[(base) + arow + ((half) * 4 + mi) * 512];

#define READ_B(base)                                                            \
    _Pragma("unroll")                                                           \
    for (int ni = 0; ni < 4; ++ni)                                              \
        bf[ni] = *(const bf16x8*)&lds[(base) + brow + ni * 512];

#define MFMA16(half)                                                            \
    __builtin_amdgcn_s_setprio(1);                                              \
    _Pragma("unroll")                                                           \
    for (int mi = 0; mi < 4; ++mi)                                              \
        _Pragma("unroll")                                                       \
        for (int ni = 0; ni < 4; ++ni)                                          \
            acc[(half) * 4 + mi][ni] = __builtin_amdgcn_mfma_f32_16x16x32_bf16( \
                af[mi], bf[ni], acc[(half) * 4 + mi][ni], 0, 0, 0);             \
    __builtin_amdgcn_s_setprio(0);

__global__ __launch_bounds__(512, 1) void gemm_conv_kernel(
    const unsigned short* __restrict__ Ap,   // [256][2304] bf16
    const unsigned short* __restrict__ Xp,   // [226][226][256] bf16
    float* __restrict__ out)                 // [256][50176]
{
    __shared__ unsigned short lds[65536];    // 128 KB

    const int tid = threadIdx.x;
    const int Nb = blockIdx.x;               // 0..195
    const int wave = tid >> 6;               // 0..7
    const int wm = wave >> 2;                // 0..1 (M half: 128 rows)
    const int wn = wave & 3;                 // 0..3 (N quarter: 64 cols)
    const int lane = tid & 63;
    const int ln15 = lane & 15;
    const int quad = lane >> 4;
    const int slot8 = (quad ^ (ln15 & 3)) * 8;           // conflict-free read slot
    const int arow = (wm * 128 + ln15) * 32 + slot8;     // + (half*4+mi)*512
    const int brow = 32768 + (wn * 64 + ln15) * 32 + slot8;  // + ni*512

    // ---- staging sources (inverse swizzle pre-applied) ----
    const int c4 = (tid & 3) ^ ((tid >> 2) & 3);
    const unsigned short* a_src[2];
    const unsigned short* b_src[2];
#pragma unroll
    for (int j = 0; j < 2; ++j) {
        const int r = j * 128 + (tid >> 2);              // 0..255
        a_src[j] = Ap + r * KDIM + c4 * 8;               // + kt*64 + kappa*32
        unsigned int p = Nb * 256 + r;
        unsigned int hi = p / W, wi = p - hi * W;
        b_src[j] = Xp + (hi * HP + wi) * CI + c4 * 8;    // + tap/ci offset
    }

    f32x4 acc[8][4];
#pragma unroll
    for (int mi = 0; mi < 8; ++mi)
#pragma unroll
        for (int ni = 0; ni < 4; ++ni)
            acc[mi][ni] = (f32x4){0.f, 0.f, 0.f, 0.f};

    auto stageA = [&](int kt, int k) {
        const int dst = ((kt & 1) * 2 + k) * 8192;
        const int off = kt * 64 + k * 32;
#pragma unroll
        for (int j = 0; j < 2; ++j)
            load_lds16(a_src[j] + off, &lds[dst + (j * 8 + wave) * 512]);
    };
    auto stageB = [&](int kt, int k) {
        const int dst = 32768 + ((kt & 1) * 2 + k) * 8192;
        const int tap = kt >> 2;                         // 0..8
        const int dh = (tap * 11) >> 5;                  // tap/3 for tap<=8
        const int dw = tap - dh * 3;
        const int off = (dh * HP + dw) * CI + (kt & 3) * 64 + k * 32;
#pragma unroll
        for (int j = 0; j < 2; ++j)
            load_lds16(b_src[j] + off, &lds[dst + (j * 8 + wave) * 512]);
    };

    bf16x8 af[4], bf[4];

    // ---- prologue: stage K-tile 0 (Ak0,Bk0,Ak1,Bk1 = 8 loads); keep k1 in flight ----
    stageA(0, 0); stageB(0, 0); stageA(0, 1); stageB(0, 1);
    asm volatile("s_waitcnt vmcnt(4)" ::: "memory");     // Ak0,Bk0 landed
    __builtin_amdgcn_s_barrier();

    for (int kt = 0; kt < 36; ++kt) {
        const int pi = (kt & 1) * 2;
        const int b0 = pi * 8192;                        // kappa = 0 region
        const int b1 = (pi + 1) * 8192;                  // kappa = 1 region
        const bool st = kt < 35;
        // ---- P1 ----
        READ_A(b0, 0) READ_B(b0)
        if (st) stageA(kt + 1, 0);
        __builtin_amdgcn_s_barrier();
        asm volatile("s_waitcnt lgkmcnt(0)" ::: "memory");
        __builtin_amdgcn_sched_barrier(0);
        MFMA16(0)
        __builtin_amdgcn_s_barrier();
        // ---- P2 ----
        READ_A(b0, 1)
        if (st) {
            stageB(kt + 1, 0);
            asm volatile("s_waitcnt vmcnt(4)" ::: "memory");
        } else {
            asm volatile("s_waitcnt vmcnt(0)" ::: "memory");
        }
        __builtin_amdgcn_s_barrier();
        asm volatile("s_waitcnt lgkmcnt(0)" ::: "memory");
        __builtin_amdgcn_sched_barrier(0);
        MFMA16(1)
        __builtin_amdgcn_s_barrier();
        // ---- P3 ----
        READ_A(b1, 0) READ_B(b1)
        if (st) stageA(kt + 1, 1);
        __builtin_amdgcn_s_barrier();
        asm volatile("s_waitcnt lgkmcnt(0)" ::: "memory");
        __builtin_amdgcn_sched_barrier(0);
        MFMA16(0)
        __builtin_amdgcn_s_barrier();
        // ---- P4 ----
        READ_A(b1, 1)
        if (st) {
            stageB(kt + 1, 1);
            asm volatile("s_waitcnt vmcnt(4)" ::: "memory");
        }
        __builtin_amdgcn_s_barrier();
        asm volatile("s_waitcnt lgkmcnt(0)" ::: "memory");
        __builtin_amdgcn_sched_barrier(0);
        MFMA16(1)
        __builtin_amdgcn_s_barrier();
    }

    // ---- epilogue: C/D layout col = lane&15 (n=p), row = quad*4 + reg (m=co) ----
    const int pcol = Nb * 256 + wn * 64 + ln15;
    const int corow = wm * 128 + quad * 4;
#pragma unroll
    for (int mi = 0; mi < 8; ++mi)
#pragma unroll
        for (int ni = 0; ni < 4; ++ni)
#pragma unroll
            for (int r = 0; r < 4; ++r)
                out[(corow + mi * 16 + r) * NPOS + pcol + ni * 16] = acc[mi][ni][r];
}

extern "C" void kernel_launch(void* const* d_in, const int* in_sizes, int n_in,
                              void* d_out, int out_size, void* d_ws, size_t ws_size,
                              hipStream_t stream) {
    const float* x = (const float*)d_in[0];       // [1,256,224,224]
    const float* w = (const float*)d_in[1];       // [256,256,3,3]
    float* out = (float*)d_out;                   // [256,224,224]

    unsigned short* xp = (unsigned short*)d_ws;        // 13,075,456 shorts
    unsigned short* ap = xp + XP_ELEMS;                // 589,824 shorts

    prep_kernel<<<XT_BLOCKS + WT_BLOCKS + 113, 256, 0, stream>>>(x, w, ap, xp);
    gemm_conv_kernel<<<dim3(NPOS / 256), 512, 0, stream>>>(ap, xp, out);
}

// Round 6
// 158.637 us; speedup vs baseline: 1.1844x; 1.0356x over previous
//
#include <hip/hip_runtime.h>

// Conv2d 3x3 pad1 stride1, x[1,256,224,224] f32, w[256,256,3,3] f32 -> out[256,224,224] f32
// Implicit GEMM: M=256 (co), N=50176 (h*224+w), K=2304 (tap-major: k = (dh*3+dw)*256 + ci)
// R12: conflict-free swizzle fix on R11. R11's counters proved EXACTLY +4 conflict-cycles
//      per ds_read_b128 (5,419,008 / 1,354,752 = 4.0): slot=quad^(ln15&3) puts 4 lanes on
//      each 16B bank-group within every 16-lane service group (balanced min = 2). New
//      slot = quad^((ln15>>1)&3): every 8/16/32/64-lane subgroup perfectly balanced
//      (octet hits all 8 bank-quads distinct). Store-side source chunk changes to match:
//      c4 = (l&3)^((l>>3)&3). Lane still receives global chunk = quad -> MFMA inputs
//      bitwise identical to R11. Two-line diff vs R11 = clean A/B on the conflict counter.

#define H 224
#define W 224
#define NPOS (H*W)          // 50176
#define CI 256
#define CO 256
#define KDIM 2304
#define HP 226              // padded
#define XP_ELEMS (HP*HP*CI) // 13,075,456 shorts
#define AP_ELEMS (CO*KDIM)  // 589,824 shorts

typedef __bf16 bf16x8 __attribute__((ext_vector_type(8)));
typedef float f32x4 __attribute__((ext_vector_type(4)));
typedef unsigned short u16x4 __attribute__((ext_vector_type(4)));
typedef unsigned short u16x8 __attribute__((ext_vector_type(8)));

__device__ __forceinline__ unsigned short f2bf(float f) {
    unsigned int u = __float_as_uint(f);
    u += 0x7fff + ((u >> 16) & 1);   // round-to-nearest-even
    return (unsigned short)(u >> 16);
}

__device__ __forceinline__ void load_lds16(const unsigned short* g, unsigned short* l) {
    __builtin_amdgcn_global_load_lds(
        (const __attribute__((address_space(1))) void*)g,
        (__attribute__((address_space(3))) void*)l,
        16, 0, 0);
}

// ---- fused prep (unchanged from R8): xtrans + weight transform + border zero ----
#define XT_BLOCKS 3136      // 784 * 4
#define WT_BLOCKS 256
#define BORDER_V8 28800     // 230,400 shorts / 8
#define ROW_V8 7232         // 226*256/8
__global__ void prep_kernel(const float* __restrict__ x, const float* __restrict__ w,
                            unsigned short* __restrict__ ap, unsigned short* __restrict__ xp) {
    __shared__ unsigned short smem[64 * 68];
    const int bx = blockIdx.x;
    const int t = threadIdx.x;

    if (bx < XT_BLOCKS) {
        const unsigned int pBase = (unsigned int)(bx % 784) * 64;
        const unsigned int ciBase = (unsigned int)(bx / 784) * 64;
        {
            const int p4 = (t & 15) * 4;
            const int c0 = t >> 4;               // 0..15
#pragma unroll
            for (int i = 0; i < 4; ++i) {
                const int ci_l = c0 + i * 16;
                const f32x4 v = *(const f32x4*)&x[(ciBase + ci_l) * NPOS + pBase + p4];
                u16x4 s;
                s[0] = f2bf(v[0]); s[1] = f2bf(v[1]); s[2] = f2bf(v[2]); s[3] = f2bf(v[3]);
                *(u16x4*)&smem[ci_l * 68 + p4] = s;
            }
        }
        __syncthreads();
        {
            const int ci0 = (t & 7) * 8;
            const int pr = t >> 3;               // 0..31
#pragma unroll
            for (int j = 0; j < 2; ++j) {
                const int p_l = pr + j * 32;
                const unsigned int p = pBase + p_l;
                const unsigned int hi = p / W, wi = p - hi * W;
                u16x8 v;
#pragma unroll
                for (int k = 0; k < 8; ++k) v[k] = smem[(ci0 + k) * 68 + p_l];
                *(u16x8*)&xp[((hi + 1) * HP + (wi + 1)) * CI + ciBase + ci0] = v;
            }
        }
    } else if (bx < XT_BLOCKS + WT_BLOCKS) {
        const int co = bx - XT_BLOCKS;
        const float* wc = w + co * KDIM;
#pragma unroll
        for (int i = 0; i < 9; ++i)
            smem[i * 256 + t] = f2bf(wc[i * 256 + t]);
        __syncthreads();
        unsigned short* apc = ap + co * KDIM;
#pragma unroll
        for (int tap = 0; tap < 9; ++tap)
            apc[tap * 256 + t] = smem[t * 9 + tap];
    } else {
        const int idx = (bx - XT_BLOCKS - WT_BLOCKS) * 256 + t;
        if (idx < BORDER_V8) {
            unsigned short* p;
            if (idx < 2 * ROW_V8) {
                const int r = idx / ROW_V8;
                const int off = idx - r * ROW_V8;
                p = xp + r * (225 * HP * CI) + off * 8;
            } else {
                const int i2 = idx - 2 * ROW_V8;
                const int seg = i2 >> 5;
                const int o = i2 & 31;
                const int hp = 1 + (seg >> 1);
                const int wp = (seg & 1) * 225;
                p = xp + (hp * HP + wp) * CI + o * 8;
            }
            *(u16x8*)p = (u16x8){0, 0, 0, 0, 0, 0, 0, 0};
        }
    }
}

// ---- implicit GEMM, 8-phase, 256x256 tile, BK=64 (structure identical to R11) ----
// LDS (shorts): A[pi][kappa] = 4 regions x 8192 at [0,32768); B likewise at +32768.
//   Region layout: 256 rows x 32 shorts (64B); slot s of row r holds global chunk
//   s ^ ((r&15)>>1 & 3) (16B chunks). gload_lds writes linearly; inverse swizzle
//   pre-applied to global source chunk per thread: c4 = (l&3)^((l>>3)&3).
// Bank analysis (32 banks, 16B bank-quads, quad8 = addr/16 mod 8):
//   read lane (quad,ln15): quad8 = 4*(ln15&1) + (quad^((ln15>>1)&3)).
//   Octet lanes 0-7: {0,4,1,5,2,6,3,7} all distinct; every 16-lane group: each quad8
//   exactly 2x (minimum); full wave: 8x (minimum). Balanced at every granularity.
// Phases/waits identical to R11 (vmcnt(4) twice per K-tile, never 0 in loop).

#define READ_A(base, half)                                                      \
    _Pragma("unroll")                                                           \
    for (int mi = 0; mi < 4; ++mi)                                              \
        af[mi] = *(const bf16x8*)&lds[(base) + arow + ((half) * 4 + mi) * 512];

#define READ_B(base)                                                            \
    _Pragma("unroll")                                                           \
    for (int ni = 0; ni < 4; ++ni)                                              \
        bf[ni] = *(const bf16x8*)&lds[(base) + brow + ni * 512];

#define MFMA16(half)                                                            \
    __builtin_amdgcn_s_setprio(1);                                              \
    _Pragma("unroll")                                                           \
    for (int mi = 0; mi < 4; ++mi)                                              \
        _Pragma("unroll")                                                       \
        for (int ni = 0; ni < 4; ++ni)                                          \
            acc[(half) * 4 + mi][ni] = __builtin_amdgcn_mfma_f32_16x16x32_bf16( \
                af[mi], bf[ni], acc[(half) * 4 + mi][ni], 0, 0, 0);             \
    __builtin_amdgcn_s_setprio(0);

__global__ __launch_bounds__(512, 1) void gemm_conv_kernel(
    const unsigned short* __restrict__ Ap,   // [256][2304] bf16
    const unsigned short* __restrict__ Xp,   // [226][226][256] bf16
    float* __restrict__ out)                 // [256][50176]
{
    __shared__ unsigned short lds[65536];    // 128 KB

    const int tid = threadIdx.x;
    const int Nb = blockIdx.x;               // 0..195
    const int wave = tid >> 6;               // 0..7
    const int wm = wave >> 2;                // 0..1 (M half: 128 rows)
    const int wn = wave & 3;                 // 0..3 (N quarter: 64 cols)
    const int lane = tid & 63;
    const int ln15 = lane & 15;
    const int quad = lane >> 4;
    const int slot8 = (quad ^ ((ln15 >> 1) & 3)) * 8;    // conflict-free read slot (R12)
    const int arow = (wm * 128 + ln15) * 32 + slot8;     // + (half*4+mi)*512
    const int brow = 32768 + (wn * 64 + ln15) * 32 + slot8;  // + ni*512

    // ---- staging sources (inverse swizzle pre-applied; R12: bits 3-4 of lane) ----
    const int c4 = (tid & 3) ^ ((tid >> 3) & 3);
    const unsigned short* a_src[2];
    const unsigned short* b_src[2];
#pragma unroll
    for (int j = 0; j < 2; ++j) {
        const int r = j * 128 + (tid >> 2);              // 0..255
        a_src[j] = Ap + r * KDIM + c4 * 8;               // + kt*64 + kappa*32
        unsigned int p = Nb * 256 + r;
        unsigned int hi = p / W, wi = p - hi * W;
        b_src[j] = Xp + (hi * HP + wi) * CI + c4 * 8;    // + tap/ci offset
    }

    f32x4 acc[8][4];
#pragma unroll
    for (int mi = 0; mi < 8; ++mi)
#pragma unroll
        for (int ni = 0; ni < 4; ++ni)
            acc[mi][ni] = (f32x4){0.f, 0.f, 0.f, 0.f};

    auto stageA = [&](int kt, int k) {
        const int dst = ((kt & 1) * 2 + k) * 8192;
        const int off = kt * 64 + k * 32;
#pragma unroll
        for (int j = 0; j < 2; ++j)
            load_lds16(a_src[j] + off, &lds[dst + (j * 8 + wave) * 512]);
    };
    auto stageB = [&](int kt, int k) {
        const int dst = 32768 + ((kt & 1) * 2 + k) * 8192;
        const int tap = kt >> 2;                         // 0..8
        const int dh = (tap * 11) >> 5;                  // tap/3 for tap<=8
        const int dw = tap - dh * 3;
        const int off = (dh * HP + dw) * CI + (kt & 3) * 64 + k * 32;
#pragma unroll
        for (int j = 0; j < 2; ++j)
            load_lds16(b_src[j] + off, &lds[dst + (j * 8 + wave) * 512]);
    };

    bf16x8 af[4], bf[4];

    // ---- prologue: stage K-tile 0 (Ak0,Bk0,Ak1,Bk1 = 8 loads); keep k1 in flight ----
    stageA(0, 0); stageB(0, 0); stageA(0, 1); stageB(0, 1);
    asm volatile("s_waitcnt vmcnt(4)" ::: "memory");     // Ak0,Bk0 landed
    __builtin_amdgcn_s_barrier();

    for (int kt = 0; kt < 36; ++kt) {
        const int pi = (kt & 1) * 2;
        const int b0 = pi * 8192;                        // kappa = 0 region
        const int b1 = (pi + 1) * 8192;                  // kappa = 1 region
        const bool st = kt < 35;
        // ---- P1 ----
        READ_A(b0, 0) READ_B(b0)
        if (st) stageA(kt + 1, 0);
        __builtin_amdgcn_s_barrier();
        asm volatile("s_waitcnt lgkmcnt(0)" ::: "memory");
        __builtin_amdgcn_sched_barrier(0);
        MFMA16(0)
        __builtin_amdgcn_s_barrier();
        // ---- P2 ----
        READ_A(b0, 1)
        if (st) {
            stageB(kt + 1, 0);
            asm volatile("s_waitcnt vmcnt(4)" ::: "memory");
        } else {
            asm volatile("s_waitcnt vmcnt(0)" ::: "memory");
        }
        __builtin_amdgcn_s_barrier();
        asm volatile("s_waitcnt lgkmcnt(0)" ::: "memory");
        __builtin_amdgcn_sched_barrier(0);
        MFMA16(1)
        __builtin_amdgcn_s_barrier();
        // ---- P3 ----
        READ_A(b1, 0) READ_B(b1)
        if (st) stageA(kt + 1, 1);
        __builtin_amdgcn_s_barrier();
        asm volatile("s_waitcnt lgkmcnt(0)" ::: "memory");
        __builtin_amdgcn_sched_barrier(0);
        MFMA16(0)
        __builtin_amdgcn_s_barrier();
        // ---- P4 ----
        READ_A(b1, 1)
        if (st) {
            stageB(kt + 1, 1);
            asm volatile("s_waitcnt vmcnt(4)" ::: "memory");
        }
        __builtin_amdgcn_s_barrier();
        asm volatile("s_waitcnt lgkmcnt(0)" ::: "memory");
        __builtin_amdgcn_sched_barrier(0);
        MFMA16(1)
        __builtin_amdgcn_s_barrier();
    }

    // ---- epilogue: C/D layout col = lane&15 (n=p), row = quad*4 + reg (m=co) ----
    const int pcol = Nb * 256 + wn * 64 + ln15;
    const int corow = wm * 128 + quad * 4;
#pragma unroll
    for (int mi = 0; mi < 8; ++mi)
#pragma unroll
        for (int ni = 0; ni < 4; ++ni)
#pragma unroll
            for (int r = 0; r < 4; ++r)
                out[(corow + mi * 16 + r) * NPOS + pcol + ni * 16] = acc[mi][ni][r];
}

extern "C" void kernel_launch(void* const* d_in, const int* in_sizes, int n_in,
                              void* d_out, int out_size, void* d_ws, size_t ws_size,
                              hipStream_t stream) {
    const float* x = (const float*)d_in[0];       // [1,256,224,224]
    const float* w = (const float*)d_in[1];       // [256,256,3,3]
    float* out = (float*)d_out;                   // [256,224,224]

    unsigned short* xp = (unsigned short*)d_ws;        // 13,075,456 shorts
    unsigned short* ap = xp + XP_ELEMS;                // 589,824 shorts

    prep_kernel<<<XT_BLOCKS + WT_BLOCKS + 113, 256, 0, stream>>>(x, w, ap, xp);
    gemm_conv_kernel<<<dim3(NPOS / 256), 512, 0, stream>>>(ap, xp, out);
}

// Round 7
// 154.002 us; speedup vs baseline: 1.2201x; 1.0301x over previous
//
#include <hip/hip_runtime.h>

// Conv2d 3x3 pad1 stride1, x[1,256,224,224] f32, w[256,256,3,3] f32 -> out[256,224,224] f32
// Implicit GEMM: M=256 (co), N=50176 (h*224+w), K=2304 (tap-major: k = (dh*3+dw)*256 + ci)
// R13: barrier relaxation on R12. R12 proved conflicts=0 yet 52% of MFMA floor: the
//      8-barrier/K-tile lockstep serializes (ds_read + lgkm-join) with MFMA CU-wide.
//      Within a K-tile, reads (buffer pi) and stage-writes (buffer 1-pi) are disjoint ->
//      only the two vmcnt-propagation points are required. New loop: per kappa half
//      {12|12 ds_read ; stage 2 ; 32 MFMA free-run ; vmcnt(4) ; s_barrier} = 2 barriers
//      per K-tile (was 8). No manual lgkm0/sched_barrier (compiler emits fine-grained
//      lgkm waits). Waves anti-phase: reads of one overlap MFMAs of another (setprio
//      arbitration). Indexing/accumulation order identical to R12 -> bitwise-same output.

#define H 224
#define W 224
#define NPOS (H*W)          // 50176
#define CI 256
#define CO 256
#define KDIM 2304
#define HP 226              // padded
#define XP_ELEMS (HP*HP*CI) // 13,075,456 shorts
#define AP_ELEMS (CO*KDIM)  // 589,824 shorts

typedef __bf16 bf16x8 __attribute__((ext_vector_type(8)));
typedef float f32x4 __attribute__((ext_vector_type(4)));
typedef unsigned short u16x4 __attribute__((ext_vector_type(4)));
typedef unsigned short u16x8 __attribute__((ext_vector_type(8)));

__device__ __forceinline__ unsigned short f2bf(float f) {
    unsigned int u = __float_as_uint(f);
    u += 0x7fff + ((u >> 16) & 1);   // round-to-nearest-even
    return (unsigned short)(u >> 16);
}

__device__ __forceinline__ void load_lds16(const unsigned short* g, unsigned short* l) {
    __builtin_amdgcn_global_load_lds(
        (const __attribute__((address_space(1))) void*)g,
        (__attribute__((address_space(3))) void*)l,
        16, 0, 0);
}

// ---- fused prep (unchanged from R8): xtrans + weight transform + border zero ----
#define XT_BLOCKS 3136      // 784 * 4
#define WT_BLOCKS 256
#define BORDER_V8 28800     // 230,400 shorts / 8
#define ROW_V8 7232         // 226*256/8
__global__ void prep_kernel(const float* __restrict__ x, const float* __restrict__ w,
                            unsigned short* __restrict__ ap, unsigned short* __restrict__ xp) {
    __shared__ unsigned short smem[64 * 68];
    const int bx = blockIdx.x;
    const int t = threadIdx.x;

    if (bx < XT_BLOCKS) {
        const unsigned int pBase = (unsigned int)(bx % 784) * 64;
        const unsigned int ciBase = (unsigned int)(bx / 784) * 64;
        {
            const int p4 = (t & 15) * 4;
            const int c0 = t >> 4;               // 0..15
#pragma unroll
            for (int i = 0; i < 4; ++i) {
                const int ci_l = c0 + i * 16;
                const f32x4 v = *(const f32x4*)&x[(ciBase + ci_l) * NPOS + pBase + p4];
                u16x4 s;
                s[0] = f2bf(v[0]); s[1] = f2bf(v[1]); s[2] = f2bf(v[2]); s[3] = f2bf(v[3]);
                *(u16x4*)&smem[ci_l * 68 + p4] = s;
            }
        }
        __syncthreads();
        {
            const int ci0 = (t & 7) * 8;
            const int pr = t >> 3;               // 0..31
#pragma unroll
            for (int j = 0; j < 2; ++j) {
                const int p_l = pr + j * 32;
                const unsigned int p = pBase + p_l;
                const unsigned int hi = p / W, wi = p - hi * W;
                u16x8 v;
#pragma unroll
                for (int k = 0; k < 8; ++k) v[k] = smem[(ci0 + k) * 68 + p_l];
                *(u16x8*)&xp[((hi + 1) * HP + (wi + 1)) * CI + ciBase + ci0] = v;
            }
        }
    } else if (bx < XT_BLOCKS + WT_BLOCKS) {
        const int co = bx - XT_BLOCKS;
        const float* wc = w + co * KDIM;
#pragma unroll
        for (int i = 0; i < 9; ++i)
            smem[i * 256 + t] = f2bf(wc[i * 256 + t]);
        __syncthreads();
        unsigned short* apc = ap + co * KDIM;
#pragma unroll
        for (int tap = 0; tap < 9; ++tap)
            apc[tap * 256 + t] = smem[t * 9 + tap];
    } else {
        const int idx = (bx - XT_BLOCKS - WT_BLOCKS) * 256 + t;
        if (idx < BORDER_V8) {
            unsigned short* p;
            if (idx < 2 * ROW_V8) {
                const int r = idx / ROW_V8;
                const int off = idx - r * ROW_V8;
                p = xp + r * (225 * HP * CI) + off * 8;
            } else {
                const int i2 = idx - 2 * ROW_V8;
                const int seg = i2 >> 5;
                const int o = i2 & 31;
                const int hp = 1 + (seg >> 1);
                const int wp = (seg & 1) * 225;
                p = xp + (hp * HP + wp) * CI + o * 8;
            }
            *(u16x8*)p = (u16x8){0, 0, 0, 0, 0, 0, 0, 0};
        }
    }
}

// ---- implicit GEMM, 256x256 tile, BK=64, 8 waves (2Mx4N), wave-tile 128x64 ----
// LDS (shorts): A[pi][kappa] = 4 regions x 8192 at [0,32768); B likewise at +32768.
//   Slot s of row r holds global chunk s ^ ((r&15)>>1 & 3); inverse pre-applied to
//   global source (c4 = (l&3)^((l>>3)&3)); read slot quad^((ln15>>1)&3) -> chunk=quad.
//   Bank-balanced at every 8/16/32/64-lane granularity (R12-verified: conflicts = 0).
// Sync points (ONLY, per K-tile): after each kappa half {vmcnt(4); s_barrier}.
//   vmcnt proof: at kappa0-end outstanding = Ak1,Bk1(kt) + Ak0,Bk0(kt+1) = 8 ->
//   vmcnt(4) retires kt's k1, read in kappa1 after the barrier. At kappa1-end
//   outstanding = kt+1's 8 -> vmcnt(4) retires Ak0,Bk0(kt+1), read next iter.
//   Stage-writes (buffer 1-pi) vs reads (pi) disjoint within a K-tile; region
//   (1-pi) last read in kt-1, sealed by kt-1's kappa1-end barrier.
// Tail kt=35: no staging; kappa0-end uses vmcnt(0) so kt=35's k1 is landed.

#define READ_A(base, half)                                                      \
    _Pragma("unroll")                                                           \
    for (int mi = 0; mi < 4; ++mi)                                              \
        af[mi] = *(const bf16x8*)&lds[(base) + arow + ((half) * 4 + mi) * 512];

#define READ_B(base)                                                            \
    _Pragma("unroll")                                                           \
    for (int ni = 0; ni < 4; ++ni)                                              \
        bf[ni] = *(const bf16x8*)&lds[(base) + brow + ni * 512];

#define MFMA16(half)                                                            \
    __builtin_amdgcn_s_setprio(1);                                              \
    _Pragma("unroll")                                                           \
    for (int mi = 0; mi < 4; ++mi)                                              \
        _Pragma("unroll")                                                       \
        for (int ni = 0; ni < 4; ++ni)                                          \
            acc[(half) * 4 + mi][ni] = __builtin_amdgcn_mfma_f32_16x16x32_bf16( \
                af[mi], bf[ni], acc[(half) * 4 + mi][ni], 0, 0, 0);             \
    __builtin_amdgcn_s_setprio(0);

__global__ __launch_bounds__(512, 1) void gemm_conv_kernel(
    const unsigned short* __restrict__ Ap,   // [256][2304] bf16
    const unsigned short* __restrict__ Xp,   // [226][226][256] bf16
    float* __restrict__ out)                 // [256][50176]
{
    __shared__ unsigned short lds[65536];    // 128 KB

    const int tid = threadIdx.x;
    const int Nb = blockIdx.x;               // 0..195
    const int wave = tid >> 6;               // 0..7
    const int wm = wave >> 2;                // 0..1 (M half: 128 rows)
    const int wn = wave & 3;                 // 0..3 (N quarter: 64 cols)
    const int lane = tid & 63;
    const int ln15 = lane & 15;
    const int quad = lane >> 4;
    const int slot8 = (quad ^ ((ln15 >> 1) & 3)) * 8;    // conflict-free read slot
    const int arow = (wm * 128 + ln15) * 32 + slot8;     // + (half*4+mi)*512
    const int brow = 32768 + (wn * 64 + ln15) * 32 + slot8;  // + ni*512

    // ---- staging sources (inverse swizzle pre-applied) ----
    const int c4 = (tid & 3) ^ ((tid >> 3) & 3);
    const unsigned short* a_src[2];
    const unsigned short* b_src[2];
#pragma unroll
    for (int j = 0; j < 2; ++j) {
        const int r = j * 128 + (tid >> 2);              // 0..255
        a_src[j] = Ap + r * KDIM + c4 * 8;               // + kt*64 + kappa*32
        unsigned int p = Nb * 256 + r;
        unsigned int hi = p / W, wi = p - hi * W;
        b_src[j] = Xp + (hi * HP + wi) * CI + c4 * 8;    // + tap/ci offset
    }

    f32x4 acc[8][4];
#pragma unroll
    for (int mi = 0; mi < 8; ++mi)
#pragma unroll
        for (int ni = 0; ni < 4; ++ni)
            acc[mi][ni] = (f32x4){0.f, 0.f, 0.f, 0.f};

    auto stageA = [&](int kt, int k) {
        const int dst = ((kt & 1) * 2 + k) * 8192;
        const int off = kt * 64 + k * 32;
#pragma unroll
        for (int j = 0; j < 2; ++j)
            load_lds16(a_src[j] + off, &lds[dst + (j * 8 + wave) * 512]);
    };
    auto stageB = [&](int kt, int k) {
        const int dst = 32768 + ((kt & 1) * 2 + k) * 8192;
        const int tap = kt >> 2;                         // 0..8
        const int dh = (tap * 11) >> 5;                  // tap/3 for tap<=8
        const int dw = tap - dh * 3;
        const int off = (dh * HP + dw) * CI + (kt & 3) * 64 + k * 32;
#pragma unroll
        for (int j = 0; j < 2; ++j)
            load_lds16(b_src[j] + off, &lds[dst + (j * 8 + wave) * 512]);
    };

    bf16x8 af[4], bf[4];

    // ---- prologue: stage K-tile 0 (Ak0,Bk0,Ak1,Bk1 = 8 loads); keep k1 in flight ----
    stageA(0, 0); stageB(0, 0); stageA(0, 1); stageB(0, 1);
    asm volatile("s_waitcnt vmcnt(4)" ::: "memory");     // Ak0,Bk0 landed
    __builtin_amdgcn_s_barrier();

    for (int kt = 0; kt < 36; ++kt) {
        const int pi = (kt & 1) * 2;
        const int b0 = pi * 8192;                        // kappa = 0 region
        const int b1 = (pi + 1) * 8192;                  // kappa = 1 region
        const bool st = kt < 35;
        // ---- kappa = 0 half: free-run (no intra barriers) ----
        READ_A(b0, 0) READ_B(b0)
        if (st) stageA(kt + 1, 0);
        MFMA16(0)
        READ_A(b0, 1)
        if (st) stageB(kt + 1, 0);
        MFMA16(1)
        if (st) asm volatile("s_waitcnt vmcnt(4)" ::: "memory");
        else    asm volatile("s_waitcnt vmcnt(0)" ::: "memory");
        __builtin_amdgcn_s_barrier();                    // kt's k1 landed, wave-global
        // ---- kappa = 1 half ----
        READ_A(b1, 0) READ_B(b1)
        if (st) stageA(kt + 1, 1);
        MFMA16(0)
        READ_A(b1, 1)
        if (st) stageB(kt + 1, 1);
        MFMA16(1)
        if (st) {
            asm volatile("s_waitcnt vmcnt(4)" ::: "memory");
            __builtin_amdgcn_s_barrier();                // kt+1's k0 landed; seals pi reads
        }
    }

    // ---- epilogue: C/D layout col = lane&15 (n=p), row = quad*4 + reg (m=co) ----
    const int pcol = Nb * 256 + wn * 64 + ln15;
    const int corow = wm * 128 + quad * 4;
#pragma unroll
    for (int mi = 0; mi < 8; ++mi)
#pragma unroll
        for (int ni = 0; ni < 4; ++ni)
#pragma unroll
            for (int r = 0; r < 4; ++r)
                out[(corow + mi * 16 + r) * NPOS + pcol + ni * 16] = acc[mi][ni][r];
}

extern "C" void kernel_launch(void* const* d_in, const int* in_sizes, int n_in,
                              void* d_out, int out_size, void* d_ws, size_t ws_size,
                              hipStream_t stream) {
    const float* x = (const float*)d_in[0];       // [1,256,224,224]
    const float* w = (const float*)d_in[1];       // [256,256,3,3]
    float* out = (float*)d_out;                   // [256,224,224]

    unsigned short* xp = (unsigned short*)d_ws;        // 13,075,456 shorts
    unsigned short* ap = xp + XP_ELEMS;                // 589,824 shorts

    prep_kernel<<<XT_BLOCKS + WT_BLOCKS + 113, 256, 0, stream>>>(x, w, ap, xp);
    gemm_conv_kernel<<<dim3(NPOS / 256), 512, 0, stream>>>(ap, xp, out);
}